// Round 11
// baseline (264.736 us; speedup 1.0000x reference)
//
#include <hip/hip_runtime.h>
#include <hip/hip_bf16.h>
#include <string.h>

// CausalSelfAttention on MI355X (gfx950), bf16 MFMA pipeline.
// R20: R19 (best, 261.07us) + ONE isolated change: attn's P^T LDS round-trip
//   (4 ds_write_b64 + 2 ds_read_b128 per wave-round, ~27% of the ~69%-busy
//   LDS pipe) replaced by the in-register cvt_pk + permlane16/32_swap
//   redistribution proven numerically correct in R10. Sync structure,
//   staging, liveness, grid all UNCHANGED from R19 — clean A/B.
//   -16KB LDS (48->32KB), bank conflicts -> 0, +8 cvt_pk +8 permlane VALU.
// Everything else identical to R19 (prep fusion, 2-phase BK=64 GEMMs,
//   vtrans, R9 attn structure: paired q-tiles, 34 uniform rounds).
// D=1024, H=16, Hd=64, B=4, T=2048.

typedef unsigned short u16;
typedef unsigned int u32;
typedef __bf16 bf16x8 __attribute__((ext_vector_type(8)));
typedef float f32x4 __attribute__((ext_vector_type(4)));
typedef unsigned int u32x2 __attribute__((ext_vector_type(2)));

#define MFMA16(a, b, c) __builtin_amdgcn_mfma_f32_16x16x32_bf16((a), (b), (c), 0, 0, 0)

__device__ __forceinline__ u16 f2bf(float f) {
  unsigned u = __float_as_uint(f);
  u += 0x7fffu + ((u >> 16) & 1u);  // RNE
  return (u16)(u >> 16);
}

__device__ __forceinline__ u32 pk2bf(float a, float b) {
  __hip_bfloat162 h = __float22bfloat162_rn(make_float2(a, b));  // v_cvt_pk_bf16_f32
  u32 r;
  memcpy(&r, &h, 4);  // register-level no-op
  return r;
}

__device__ __forceinline__ void gload_lds16(const void* g, void* l) {
  __builtin_amdgcn_global_load_lds((const __attribute__((address_space(1))) void*)g,
                                   (__attribute__((address_space(3))) void*)l, 16, 0, 0);
}

__device__ __forceinline__ u32x2 pl16swap(u32 a, u32 b) {
  return __builtin_amdgcn_permlane16_swap(a, b, false, false);
}
__device__ __forceinline__ u32x2 pl32swap(u32 a, u32 b) {
  return __builtin_amdgcn_permlane32_swap(a, b, false, false);
}
__device__ __forceinline__ bf16x8 mkfrag(u32 w0, u32 w1, u32 w2, u32 w3) {
  union { u32 w[4]; bf16x8 v; } u;
  u.w[0] = w0; u.w[1] = w1; u.w[2] = w2; u.w[3] = w3;
  return u.v;
}

// ---------------- prep: cast x (fp32->bf16) + transpose-cast both weights ----------------
// blocks [0,8192): cast_x; [8192,11264): tcast Wqkv (96x32); [11264,12288): tcast Wout (32x32)
__global__ __launch_bounds__(256) void prep_kernel(const float* __restrict__ x,
                                                   u16* __restrict__ xb,
                                                   const float* __restrict__ Wqkv,
                                                   u16* __restrict__ wqt,
                                                   const float* __restrict__ Wout,
                                                   u16* __restrict__ wot) {
  const int id = blockIdx.x;
  if (id < 8192) {
    int i = id * 256 + threadIdx.x;
    float4 v = ((const float4*)x)[i];
    ushort4 o;
    o.x = f2bf(v.x); o.y = f2bf(v.y); o.z = f2bf(v.z); o.w = f2bf(v.w);
    ((ushort4*)xb)[i] = o;
    return;
  }
  __shared__ float tile[32][33];
  const float* W; u16* Wt; int N, n0, k0;
  const int K = 1024;
  if (id < 11264) {
    int t = id - 8192;  W = Wqkv; Wt = wqt; N = 3072; n0 = (t % 96) * 32; k0 = (t / 96) * 32;
  } else {
    int t = id - 11264; W = Wout; Wt = wot; N = 1024; n0 = (t % 32) * 32; k0 = (t / 32) * 32;
  }
  int tx = threadIdx.x & 31, ty = threadIdx.x >> 5;  // 32 x 8
#pragma unroll
  for (int i = 0; i < 4; i++) {
    int k = ty + i * 8;
    tile[k][tx] = W[(size_t)(k0 + k) * N + n0 + tx];
  }
  __syncthreads();
#pragma unroll
  for (int i = 0; i < 4; i++) {
    int n = ty + i * 8;
    Wt[(size_t)(n0 + n) * K + k0 + tx] = f2bf(tile[tx][n]);
  }
}

// ---------------- QKV GEMM: C[8192][3072] = xb @ Wqkvt^T + bias, scatter to Q/K/V ----------------
// BK=64, 2-phase, chunk-XOR LDS swizzle. Q cols scaled by log2(e)/8 so
// attention uses raw v_exp_f32 (= 2^x). Coalesced [bh][t][64] scatter.
__global__ __launch_bounds__(256) void gemm_qkv_kernel(const u16* __restrict__ A,
                                                       const u16* __restrict__ Bt,
                                                       const float* __restrict__ bias,
                                                       u16* __restrict__ QKV) {
  __shared__ u16 As[128 * 64];  // 16 KB
  __shared__ u16 Bs[128 * 64];  // 16 KB
  const int tid = threadIdx.x, w = tid >> 6, lane = tid & 63;
  const int g = lane >> 4, c = lane & 15;
  const int wr = w >> 1, wc = w & 1;
  const int m0 = blockIdx.y * 128, n0 = blockIdx.x * 128;
  const int srow = lane >> 3;                 // 0..7 within 8-row group
  const int sch = (lane & 7) ^ srow;          // inverse-swizzled source chunk
  const int cx = c & 7;                       // read-side row&7

  f32x4 acc[4][4];
#pragma unroll
  for (int i = 0; i < 4; i++)
#pragma unroll
    for (int j = 0; j < 4; j++) acc[i][j] = (f32x4){0.f, 0.f, 0.f, 0.f};

  for (int k0 = 0; k0 < 1024; k0 += 64) {
    __syncthreads();
#pragma unroll
    for (int i = 0; i < 4; i++) {
      int row = w * 32 + i * 8;  // wave stages rows w*32..w*32+31 (8/instr)
      gload_lds16(A + (size_t)(m0 + row + srow) * 1024 + k0 + sch * 8,
                  (char*)As + row * 128);
      gload_lds16(Bt + (size_t)(n0 + row + srow) * 1024 + k0 + sch * 8,
                  (char*)Bs + row * 128);
    }
    __syncthreads();

#pragma unroll
    for (int kk = 0; kk < 2; kk++) {
      bf16x8 af[4], bf[4];
#pragma unroll
      for (int mt = 0; mt < 4; mt++)
        af[mt] = *(const bf16x8*)(As + (wr * 64 + mt * 16 + c) * 64 + ((kk * 4 + g) ^ cx) * 8);
#pragma unroll
      for (int nt = 0; nt < 4; nt++)
        bf[nt] = *(const bf16x8*)(Bs + (wc * 64 + nt * 16 + c) * 64 + ((kk * 4 + g) ^ cx) * 8);
#pragma unroll
      for (int mt = 0; mt < 4; mt++)
#pragma unroll
        for (int nt = 0; nt < 4; nt++) acc[mt][nt] = MFMA16(af[mt], bf[nt], acc[mt][nt]);
    }
  }

  const float qscale = (n0 < 1024) ? 0.18033688011112042f : 1.0f;  // log2(e)/8
  float bn[4];
#pragma unroll
  for (int nt = 0; nt < 4; nt++) bn[nt] = bias[n0 + wc * 64 + nt * 16 + c];
#pragma unroll
  for (int mt = 0; mt < 4; mt++) {
#pragma unroll
    for (int r = 0; r < 4; r++) {
      int m = m0 + wr * 64 + mt * 16 + g * 4 + r;  // token index
      int bb = m >> 11, t = m & 2047;
#pragma unroll
      for (int nt = 0; nt < 4; nt++) {
        int n = n0 + wc * 64 + nt * 16 + c;
        int which = n >> 10, rem = n & 1023, h = rem >> 6, d = rem & 63;
        float v = (acc[mt][nt][r] + bn[nt]) * qscale;
        QKV[(size_t)which * 8388608 + (((size_t)(bb * 16 + h) * 2048 + t) * 64 + d)] = f2bf(v);
      }
    }
  }
}

// ---------------- V transpose: V[bh][2048][64] -> Vt tiled [bh][kt][64d][64k] ----------------
__global__ __launch_bounds__(256) void vtrans_kernel(const u16* __restrict__ V,
                                                     u16* __restrict__ Vt) {
  __shared__ u16 tile[64][65];
  int bh = blockIdx.y;
  int kt = blockIdx.x;
  int t0 = kt * 64;
  int tx = threadIdx.x & 63, ty = threadIdx.x >> 6;  // 64 x 4
  const u16* src = V + ((size_t)bh * 2048 + t0) * 64;
#pragma unroll
  for (int i = 0; i < 16; i++) {
    int tr = i * 4 + ty;
    tile[tr][tx] = src[tr * 64 + tx];
  }
  __syncthreads();
  u16* dst = Vt + ((size_t)(bh * 32 + kt)) * 4096;  // [64d][64k] tile
#pragma unroll
  for (int i = 0; i < 16; i++) {
    int d = i * 4 + ty;
    dst[d * 64 + tx] = tile[tx][d];
  }
}

// ---------------- flash attention: paired 128-row q-tiles, 8 waves x 16 q-rows ----------------
// grid (8 pairs, 16 heads, 4 batch), 512 threads (8 waves). Block handles
// q-tiles p and 15-p (128 rows each) sequentially: 34 uniform rounds.
// Wave w owns q-rows tile_base + w*16 .. +16. K/V staged in LDS dbuf (one
// gload each per wave per round), one barrier per round. S^T = mfma(K, Q);
// p = exp2(s) (Q pre-scaled by log2e/8); P^T -> B-frag redistribution fully
// in-register via cvt_pk + permlane32/16_swap (R10-proven); l via ones-MFMA.
__global__ __launch_bounds__(512, 4) void attn_kernel(const u16* __restrict__ Q,
                                                      const u16* __restrict__ K,
                                                      const u16* __restrict__ Vt,
                                                      u16* __restrict__ ctx) {
  const int pr = blockIdx.x;          // 0..7
  const int qtA = pr, qtB = 15 - pr;  // paired 128-row q-tiles
  const int h = blockIdx.y, b = blockIdx.z;
  const int bh = b * 16 + h;
  const int tid = threadIdx.x, w = tid >> 6, lane = tid & 63;
  const int g = lane >> 4, c = lane & 15;

  const u16* Kg = K + (size_t)bh * 2048 * 64;   // [T][64]
  const u16* Vg = Vt + (size_t)bh * 32 * 4096;  // tiled [kt][64d][64k]

  __shared__ u16 Ks[2][64 * 64];   // K dbuf, XOR-swizzled chunks (16 KB)
  __shared__ u16 Vs[2][64 * 64];   // V dbuf (16 KB)

  // staging lane map (verified swizzle); wave w stages rows w*8..w*8+8
  const int srow = lane >> 3;
  const int schunk = (lane & 7) ^ (srow & 7);
  const int cx = c & 7;
  const int off0 = ((g ^ cx) * 8);        // chunk g   (u16 offset)
  const int off1 = (((g ^ cx) ^ 4) * 8);  // chunk g^4

  // constant all-ones A-fragment for the psum MFMA
  bf16x8 onesf;
#pragma unroll
  for (int i = 0; i < 8; i++) onesf[i] = (__bf16)1.0f;

  // Q B-fragments for tile A (wave's 16 q-rows; dims 0-31 / 32-63)
  const u16* QgA = Q + ((size_t)bh * 2048 + qtA * 128) * 64;
  bf16x8 aq0 = *(const bf16x8*)(QgA + (w * 16 + c) * 64 + g * 8);
  bf16x8 aq1 = *(const bf16x8*)(QgA + (w * 16 + c) * 64 + 32 + g * 8);

  // prologue: stage K/V tile 0 (1 gload each per wave)
  {
    int rbase = w * 8;
    gload_lds16(Kg + (size_t)(rbase + srow) * 64 + schunk * 8, (char*)(Ks[0]) + rbase * 128);
    gload_lds16(Vg + (size_t)(rbase + srow) * 64 + schunk * 8, (char*)(Vs[0]) + rbase * 128);
  }
  __syncthreads();

  f32x4 o[4], la;
#pragma unroll
  for (int nt = 0; nt < 4; nt++) o[nt] = (f32x4){0.f, 0.f, 0.f, 0.f};
  la = (f32x4){0.f, 0.f, 0.f, 0.f};

  const int nA = 2 * qtA + 2;  // rounds in tile A

  // normalize + packed 8B stores for one finished q-tile (wave's 16 rows)
  auto store_tile = [&](int qbase) {
    float inv = 1.f / la[0];
    int q = qbase + w * 16 + c;
    size_t base = ((size_t)(b * 2048 + q)) * 1024 + h * 64;
#pragma unroll
    for (int nt = 0; nt < 4; nt++) {
      u32 lo = pk2bf(o[nt][0] * inv, o[nt][1] * inv);
      u32 hi = pk2bf(o[nt][2] * inv, o[nt][3] * inv);
      *(uint2*)(ctx + base + nt * 16 + g * 4) = make_uint2(lo, hi);
    }
  };

  for (int r = 0; r < 34; r++) {
    if (r) __syncthreads();  // tile r staged; all waves done with buf r-1

    // prefetch round r+1's K/V tile (overlaps compute; drained at next barrier)
    if (r < 33) {
      const int ktn = (r + 1 < nA) ? (r + 1) : (r + 1 - nA);
      const int nb = (r + 1) & 1;
      int rbase = w * 8;
      gload_lds16(Kg + (size_t)ktn * 4096 + (size_t)(rbase + srow) * 64 + schunk * 8,
                  (char*)(Ks[nb]) + rbase * 128);
      gload_lds16(Vg + (size_t)ktn * 4096 + (size_t)(rbase + srow) * 64 + schunk * 8,
                  (char*)(Vs[nb]) + rbase * 128);
    }

    const bool inA = (r < nA);
    const int kt = inA ? r : (r - nA);
    const int qbase = inA ? qtA * 128 : qtB * 128;
    const int sb0 = qbase + w * 16;  // wave's first q-row
    const int kb = kt * 64;          // round's first key

    if (kb <= sb0 + 15) {  // wave-uniform: wave live this round
      const u16* Kb = Ks[r & 1];
      const u16* Vb = Vs[r & 1];

      // ---- S^T = K . Q^T : 4 key-tiles ----
      f32x4 sa[4];
#pragma unroll
      for (int nt = 0; nt < 4; nt++) {
        bf16x8 k0 = *(const bf16x8*)(Kb + (nt * 16 + c) * 64 + off0);
        bf16x8 k1 = *(const bf16x8*)(Kb + (nt * 16 + c) * 64 + off1);
        f32x4 z = (f32x4){0.f, 0.f, 0.f, 0.f};
        z = MFMA16(k0, aq0, z);  // A=K, B=Q -> S^T[key][q]
        z = MFMA16(k1, aq1, z);
        sa[nt] = z;
      }

      // ---- p = exp2(s) (lane holds keys nt*16+4g..+3 for q-col c) ----
      const bool domask = (kb + 63 > sb0);
      float pe[4][4];
#pragma unroll
      for (int nt = 0; nt < 4; nt++)
#pragma unroll
        for (int rr = 0; rr < 4; rr++) {
          float t = sa[nt][rr];
          if (domask && (kb + nt * 16 + g * 4 + rr) > (sb0 + c)) t = -1e30f;
          pe[nt][rr] = __builtin_amdgcn_exp2f(t);
        }

      // ---- in-register P^T -> B-frag redistribution (R10-proven) ----
      // source lane (g,c): key-pair words W(2g),W(2g+1) of each 16-key tile;
      // dest lane (g,c) needs words W(4g..4g+3) of each 32-key half.
      u32 wA[4], wB[4];
#pragma unroll
      for (int nt = 0; nt < 4; nt++) {
        wA[nt] = pk2bf(pe[nt][0], pe[nt][1]);  // keys 4g+0,4g+1
        wB[nt] = pk2bf(pe[nt][2], pe[nt][3]);  // keys 4g+2,4g+3
      }
      u32x2 xa0 = pl32swap(wA[0], wA[1]);
      u32x2 xb0 = pl32swap(wB[0], wB[1]);
      u32x2 ya0 = pl16swap(xa0[0], xa0[1]);  // [0]=dword0 (keys 8g+0,1), [1]=dword2
      u32x2 yb0 = pl16swap(xb0[0], xb0[1]);  // [0]=dword1, [1]=dword3
      bf16x8 pB0 = mkfrag(ya0[0], yb0[0], ya0[1], yb0[1]);  // keys 8g..8g+7, q=c
      u32x2 xa1 = pl32swap(wA[2], wA[3]);
      u32x2 xb1 = pl32swap(wB[2], wB[3]);
      u32x2 ya1 = pl16swap(xa1[0], xa1[1]);
      u32x2 yb1 = pl16swap(xb1[0], xb1[1]);
      bf16x8 pB1 = mkfrag(ya1[0], yb1[0], ya1[1], yb1[1]);  // keys 32+8g..+7

      // ---- l += P @ 1 on the MFMA pipe ----
      la = MFMA16(onesf, pB0, la);
      la = MFMA16(onesf, pB1, la);

      // ---- O^T += V^T . P^T : 4 d-tiles ----
#pragma unroll
      for (int nt = 0; nt < 4; nt++) {
        bf16x8 v0 = *(const bf16x8*)(Vb + (nt * 16 + c) * 64 + off0);
        bf16x8 v1 = *(const bf16x8*)(Vb + (nt * 16 + c) * 64 + off1);
        o[nt] = MFMA16(v0, pB0, o[nt]);
        o[nt] = MFMA16(v1, pB1, o[nt]);
      }
    }

    // transition: tile A finished -> store, reset, swap to tile B's Q
    if (r == nA - 1) {
      store_tile(qtA * 128);
#pragma unroll
      for (int nt = 0; nt < 4; nt++) o[nt] = (f32x4){0.f, 0.f, 0.f, 0.f};
      la = (f32x4){0.f, 0.f, 0.f, 0.f};
      const u16* QgB = Q + ((size_t)bh * 2048 + qtB * 128) * 64;
      aq0 = *(const bf16x8*)(QgB + (w * 16 + c) * 64 + g * 8);
      aq1 = *(const bf16x8*)(QgB + (w * 16 + c) * 64 + 32 + g * 8);
    }
  }

  store_tile(qtB * 128);
}

// ---------------- out-proj GEMM: out[8192][1024] = ctx @ Woutt^T + bias (fp32 out) ----------------
// BK=64 + chunk-XOR swizzle (R13 form).
__global__ __launch_bounds__(256) void gemm_proj_kernel(const u16* __restrict__ A,
                                                        const u16* __restrict__ Bt,
                                                        const float* __restrict__ bias,
                                                        float* __restrict__ out) {
  __shared__ u16 As[128 * 64];
  __shared__ u16 Bs[128 * 64];
  const int tid = threadIdx.x, w = tid >> 6, lane = tid & 63;
  const int g = lane >> 4, c = lane & 15;
  const int wr = w >> 1, wc = w & 1;
  const int m0 = blockIdx.y * 128, n0 = blockIdx.x * 128;
  const int srow = lane >> 3;
  const int sch = (lane & 7) ^ srow;
  const int cx = c & 7;

  f32x4 acc[4][4];
#pragma unroll
  for (int i = 0; i < 4; i++)
#pragma unroll
    for (int j = 0; j < 4; j++) acc[i][j] = (f32x4){0.f, 0.f, 0.f, 0.f};

  for (int k0 = 0; k0 < 1024; k0 += 64) {
    __syncthreads();
#pragma unroll
    for (int i = 0; i < 4; i++) {
      int row = w * 32 + i * 8;
      gload_lds16(A + (size_t)(m0 + row + srow) * 1024 + k0 + sch * 8,
                  (char*)As + row * 128);
      gload_lds16(Bt + (size_t)(n0 + row + srow) * 1024 + k0 + sch * 8,
                  (char*)Bs + row * 128);
    }
    __syncthreads();

#pragma unroll
    for (int kk = 0; kk < 2; kk++) {
      bf16x8 af[4], bf[4];
#pragma unroll
      for (int mt = 0; mt < 4; mt++)
        af[mt] = *(const bf16x8*)(As + (wr * 64 + mt * 16 + c) * 64 + ((kk * 4 + g) ^ cx) * 8);
#pragma unroll
      for (int nt = 0; nt < 4; nt++)
        bf[nt] = *(const bf16x8*)(Bs + (wc * 64 + nt * 16 + c) * 64 + ((kk * 4 + g) ^ cx) * 8);
#pragma unroll
      for (int mt = 0; mt < 4; mt++)
#pragma unroll
        for (int nt = 0; nt < 4; nt++) acc[mt][nt] = MFMA16(af[mt], bf[nt], acc[mt][nt]);
    }
  }

  float bn[4];
#pragma unroll
  for (int nt = 0; nt < 4; nt++) bn[nt] = bias[n0 + wc * 64 + nt * 16 + c];
#pragma unroll
  for (int mt = 0; mt < 4; mt++)
#pragma unroll
    for (int r = 0; r < 4; r++) {
      int m = m0 + wr * 64 + mt * 16 + g * 4 + r;
#pragma unroll
      for (int nt = 0; nt < 4; nt++) {
        int n = n0 + wc * 64 + nt * 16 + c;
        out[(size_t)m * 1024 + n] = acc[mt][nt][r] + bn[nt];
      }
    }
}

// ---------------- launch ----------------
extern "C" void kernel_launch(void* const* d_in, const int* in_sizes, int n_in,
                              void* d_out, int out_size, void* d_ws, size_t ws_size,
                              hipStream_t stream) {
  const float* x = (const float*)d_in[0];
  const float* Wqkv = (const float*)d_in[1];
  const float* bqkv = (const float*)d_in[2];
  const float* Wout = (const float*)d_in[3];
  const float* bout = (const float*)d_in[4];
  float* out = (float*)d_out;

  char* ws = (char*)d_ws;
  u16* xb  = (u16*)(ws);                    // 16 MB  x bf16 [8192][1024]
  u16* wqt = (u16*)(ws + 16777216);         //  6 MB  Wqkv^T bf16 [3072][1024]
  u16* wot = (u16*)(ws + 23068672);         //  2 MB  Wout^T bf16 [1024][1024]
  u16* Qb  = (u16*)(ws + 25165824);         // 48 MB  QKV bf16 [3][4][16][2048][64]
  u16* Kb  = Qb + 8388608;
  u16* Vb  = Kb + 8388608;
  u16* Vt  = (u16*)(ws + 75497472);         // 16 MB  V^T tiled bf16 [64bh][32kt][64d][64k]
  u16* ctx = (u16*)(ws + 92274688);         // 16 MB  attention out bf16 [8192][1024]

  prep_kernel<<<12288, 256, 0, stream>>>(x, xb, Wqkv, wqt, Wout, wot);
  gemm_qkv_kernel<<<dim3(24, 64), 256, 0, stream>>>(xb, wqt, bqkv, Qb);
  vtrans_kernel<<<dim3(32, 64), 256, 0, stream>>>(Vb, Vt);
  attn_kernel<<<dim3(8, 16, 4), 512, 0, stream>>>(Qb, Kb, Vt, ctx);
  gemm_proj_kernel<<<dim3(8, 64), 256, 0, stream>>>(ctx, wot, bout, out);
}

// Round 12
// 260.160 us; speedup vs baseline: 1.0176x; 1.0176x over previous
//
#include <hip/hip_runtime.h>
#include <hip/hip_bf16.h>
#include <string.h>

// CausalSelfAttention on MI355X (gfx950), bf16 MFMA pipeline.
// R21 == R19 (session best: 261.07us). R20's A/B proved the P^T LDS
//   round-trip BEATS in-register permlane redistribution (78.4 vs 83.1us):
//   the permlane chain is ~16 serial VALU ops on the critical path, while
//   the 6 LDS ops pipeline across 16 resident waves (bank conflicts, 2.16M,
//   are only ~2% of round time — a red herring).
// Config: prep fusion (cast_x + both weight tcasts, 1 launch); gemm_qkv/proj
//   2-phase BK=64 chunk-XOR-swizzled LDS, coalesced scatter; vtrans kernel
//   (LDS transpose, coalesced both sides); attn R9 structure: paired 128-row
//   q-tiles (uniform 34 rounds — load-balance-critical), 8 waves x 16 q-rows,
//   K/V LDS dbuf + 1 barrier/round, S^T=mfma(K,Q), exp2 softmax (Q
//   pre-scaled log2(e)/8 in gemm_qkv), l via ones-MFMA, packed P round-trip.
// Session A/B ledger (all measured): 8-phase GEMM @K=1024 neutral/worse;
//   deep-vmcnt worse; attn q-pair fusion buggy; 32-row waves worse (TLP /
//   imbalance); Vt-direct epilogue worse (uncoalesced); XCD swizzle worse
//   (L3-resident); permlane-P worse (serial VALU chain).
// D=1024, H=16, Hd=64, B=4, T=2048.

typedef unsigned short u16;
typedef unsigned int u32;
typedef __bf16 bf16x8 __attribute__((ext_vector_type(8)));
typedef float f32x4 __attribute__((ext_vector_type(4)));

#define MFMA16(a, b, c) __builtin_amdgcn_mfma_f32_16x16x32_bf16((a), (b), (c), 0, 0, 0)

__device__ __forceinline__ u16 f2bf(float f) {
  unsigned u = __float_as_uint(f);
  u += 0x7fffu + ((u >> 16) & 1u);  // RNE
  return (u16)(u >> 16);
}

__device__ __forceinline__ u32 pk2bf(float a, float b) {
  __hip_bfloat162 h = __float22bfloat162_rn(make_float2(a, b));  // v_cvt_pk_bf16_f32
  u32 r;
  memcpy(&r, &h, 4);  // register-level no-op
  return r;
}

__device__ __forceinline__ void gload_lds16(const void* g, void* l) {
  __builtin_amdgcn_global_load_lds((const __attribute__((address_space(1))) void*)g,
                                   (__attribute__((address_space(3))) void*)l, 16, 0, 0);
}

// ---------------- prep: cast x (fp32->bf16) + transpose-cast both weights ----------------
// blocks [0,8192): cast_x; [8192,11264): tcast Wqkv (96x32); [11264,12288): tcast Wout (32x32)
__global__ __launch_bounds__(256) void prep_kernel(const float* __restrict__ x,
                                                   u16* __restrict__ xb,
                                                   const float* __restrict__ Wqkv,
                                                   u16* __restrict__ wqt,
                                                   const float* __restrict__ Wout,
                                                   u16* __restrict__ wot) {
  const int id = blockIdx.x;
  if (id < 8192) {
    int i = id * 256 + threadIdx.x;
    float4 v = ((const float4*)x)[i];
    ushort4 o;
    o.x = f2bf(v.x); o.y = f2bf(v.y); o.z = f2bf(v.z); o.w = f2bf(v.w);
    ((ushort4*)xb)[i] = o;
    return;
  }
  __shared__ float tile[32][33];
  const float* W; u16* Wt; int N, n0, k0;
  const int K = 1024;
  if (id < 11264) {
    int t = id - 8192;  W = Wqkv; Wt = wqt; N = 3072; n0 = (t % 96) * 32; k0 = (t / 96) * 32;
  } else {
    int t = id - 11264; W = Wout; Wt = wot; N = 1024; n0 = (t % 32) * 32; k0 = (t / 32) * 32;
  }
  int tx = threadIdx.x & 31, ty = threadIdx.x >> 5;  // 32 x 8
#pragma unroll
  for (int i = 0; i < 4; i++) {
    int k = ty + i * 8;
    tile[k][tx] = W[(size_t)(k0 + k) * N + n0 + tx];
  }
  __syncthreads();
#pragma unroll
  for (int i = 0; i < 4; i++) {
    int n = ty + i * 8;
    Wt[(size_t)(n0 + n) * K + k0 + tx] = f2bf(tile[tx][n]);
  }
}

// ---------------- QKV GEMM: C[8192][3072] = xb @ Wqkvt^T + bias, scatter to Q/K/V ----------------
// BK=64, 2-phase, chunk-XOR LDS swizzle. Q cols scaled by log2(e)/8 so
// attention uses raw v_exp_f32 (= 2^x). Coalesced [bh][t][64] scatter.
__global__ __launch_bounds__(256) void gemm_qkv_kernel(const u16* __restrict__ A,
                                                       const u16* __restrict__ Bt,
                                                       const float* __restrict__ bias,
                                                       u16* __restrict__ QKV) {
  __shared__ u16 As[128 * 64];  // 16 KB
  __shared__ u16 Bs[128 * 64];  // 16 KB
  const int tid = threadIdx.x, w = tid >> 6, lane = tid & 63;
  const int g = lane >> 4, c = lane & 15;
  const int wr = w >> 1, wc = w & 1;
  const int m0 = blockIdx.y * 128, n0 = blockIdx.x * 128;
  const int srow = lane >> 3;                 // 0..7 within 8-row group
  const int sch = (lane & 7) ^ srow;          // inverse-swizzled source chunk
  const int cx = c & 7;                       // read-side row&7

  f32x4 acc[4][4];
#pragma unroll
  for (int i = 0; i < 4; i++)
#pragma unroll
    for (int j = 0; j < 4; j++) acc[i][j] = (f32x4){0.f, 0.f, 0.f, 0.f};

  for (int k0 = 0; k0 < 1024; k0 += 64) {
    __syncthreads();
#pragma unroll
    for (int i = 0; i < 4; i++) {
      int row = w * 32 + i * 8;  // wave stages rows w*32..w*32+31 (8/instr)
      gload_lds16(A + (size_t)(m0 + row + srow) * 1024 + k0 + sch * 8,
                  (char*)As + row * 128);
      gload_lds16(Bt + (size_t)(n0 + row + srow) * 1024 + k0 + sch * 8,
                  (char*)Bs + row * 128);
    }
    __syncthreads();

#pragma unroll
    for (int kk = 0; kk < 2; kk++) {
      bf16x8 af[4], bf[4];
#pragma unroll
      for (int mt = 0; mt < 4; mt++)
        af[mt] = *(const bf16x8*)(As + (wr * 64 + mt * 16 + c) * 64 + ((kk * 4 + g) ^ cx) * 8);
#pragma unroll
      for (int nt = 0; nt < 4; nt++)
        bf[nt] = *(const bf16x8*)(Bs + (wc * 64 + nt * 16 + c) * 64 + ((kk * 4 + g) ^ cx) * 8);
#pragma unroll
      for (int mt = 0; mt < 4; mt++)
#pragma unroll
        for (int nt = 0; nt < 4; nt++) acc[mt][nt] = MFMA16(af[mt], bf[nt], acc[mt][nt]);
    }
  }

  const float qscale = (n0 < 1024) ? 0.18033688011112042f : 1.0f;  // log2(e)/8
  float bn[4];
#pragma unroll
  for (int nt = 0; nt < 4; nt++) bn[nt] = bias[n0 + wc * 64 + nt * 16 + c];
#pragma unroll
  for (int mt = 0; mt < 4; mt++) {
#pragma unroll
    for (int r = 0; r < 4; r++) {
      int m = m0 + wr * 64 + mt * 16 + g * 4 + r;  // token index
      int bb = m >> 11, t = m & 2047;
#pragma unroll
      for (int nt = 0; nt < 4; nt++) {
        int n = n0 + wc * 64 + nt * 16 + c;
        int which = n >> 10, rem = n & 1023, h = rem >> 6, d = rem & 63;
        float v = (acc[mt][nt][r] + bn[nt]) * qscale;
        QKV[(size_t)which * 8388608 + (((size_t)(bb * 16 + h) * 2048 + t) * 64 + d)] = f2bf(v);
      }
    }
  }
}

// ---------------- V transpose: V[bh][2048][64] -> Vt tiled [bh][kt][64d][64k] ----------------
__global__ __launch_bounds__(256) void vtrans_kernel(const u16* __restrict__ V,
                                                     u16* __restrict__ Vt) {
  __shared__ u16 tile[64][65];
  int bh = blockIdx.y;
  int kt = blockIdx.x;
  int t0 = kt * 64;
  int tx = threadIdx.x & 63, ty = threadIdx.x >> 6;  // 64 x 4
  const u16* src = V + ((size_t)bh * 2048 + t0) * 64;
#pragma unroll
  for (int i = 0; i < 16; i++) {
    int tr = i * 4 + ty;
    tile[tr][tx] = src[tr * 64 + tx];
  }
  __syncthreads();
  u16* dst = Vt + ((size_t)(bh * 32 + kt)) * 4096;  // [64d][64k] tile
#pragma unroll
  for (int i = 0; i < 16; i++) {
    int d = i * 4 + ty;
    dst[d * 64 + tx] = tile[tx][d];
  }
}

// ---------------- flash attention: paired 128-row q-tiles, 8 waves x 16 q-rows ----------------
// grid (8 pairs, 16 heads, 4 batch), 512 threads (8 waves). Block handles
// q-tiles p and 15-p (128 rows each) sequentially: 34 uniform rounds.
// Wave w owns q-rows tile_base + w*16 .. +16. K/V staged in LDS dbuf (one
// gload each per wave per round), one barrier per round. S^T = mfma(K, Q);
// p = exp2(s) (Q pre-scaled by log2e/8); l via ones-MFMA psum; packed P/ctx.
__global__ __launch_bounds__(512, 4) void attn_kernel(const u16* __restrict__ Q,
                                                      const u16* __restrict__ K,
                                                      const u16* __restrict__ Vt,
                                                      u16* __restrict__ ctx) {
  const int pr = blockIdx.x;          // 0..7
  const int qtA = pr, qtB = 15 - pr;  // paired 128-row q-tiles
  const int h = blockIdx.y, b = blockIdx.z;
  const int bh = b * 16 + h;
  const int tid = threadIdx.x, w = tid >> 6, lane = tid & 63;
  const int g = lane >> 4, c = lane & 15;

  const u16* Kg = K + (size_t)bh * 2048 * 64;   // [T][64]
  const u16* Vg = Vt + (size_t)bh * 32 * 4096;  // tiled [kt][64d][64k]

  __shared__ u16 Ks[2][64 * 64];   // K dbuf, XOR-swizzled chunks (16 KB)
  __shared__ u16 Vs[2][64 * 64];   // V dbuf (16 KB)
  __shared__ u32 Pw[8][16 * 32];   // wave-private packed P^T (16 KB)
  u32* pw = Pw[w];

  // staging lane map (verified swizzle); wave w stages rows w*8..w*8+8
  const int srow = lane >> 3;
  const int schunk = (lane & 7) ^ (srow & 7);
  const int cx = c & 7;
  const int off0 = ((g ^ cx) * 8);        // chunk g   (u16 offset)
  const int off1 = (((g ^ cx) ^ 4) * 8);  // chunk g^4
  const int sw = cx << 2;                 // P-buffer 4-dword-block swizzle

  // constant all-ones A-fragment for the psum MFMA
  bf16x8 onesf;
#pragma unroll
  for (int i = 0; i < 8; i++) onesf[i] = (__bf16)1.0f;

  // Q B-fragments for tile A (wave's 16 q-rows; dims 0-31 / 32-63)
  const u16* QgA = Q + ((size_t)bh * 2048 + qtA * 128) * 64;
  bf16x8 aq0 = *(const bf16x8*)(QgA + (w * 16 + c) * 64 + g * 8);
  bf16x8 aq1 = *(const bf16x8*)(QgA + (w * 16 + c) * 64 + 32 + g * 8);

  // prologue: stage K/V tile 0 (1 gload each per wave)
  {
    int rbase = w * 8;
    gload_lds16(Kg + (size_t)(rbase + srow) * 64 + schunk * 8, (char*)(Ks[0]) + rbase * 128);
    gload_lds16(Vg + (size_t)(rbase + srow) * 64 + schunk * 8, (char*)(Vs[0]) + rbase * 128);
  }
  __syncthreads();

  f32x4 o[4], la;
#pragma unroll
  for (int nt = 0; nt < 4; nt++) o[nt] = (f32x4){0.f, 0.f, 0.f, 0.f};
  la = (f32x4){0.f, 0.f, 0.f, 0.f};

  const int nA = 2 * qtA + 2;  // rounds in tile A

  // normalize + packed 8B stores for one finished q-tile (wave's 16 rows)
  auto store_tile = [&](int qbase) {
    float inv = 1.f / la[0];
    int q = qbase + w * 16 + c;
    size_t base = ((size_t)(b * 2048 + q)) * 1024 + h * 64;
#pragma unroll
    for (int nt = 0; nt < 4; nt++) {
      u32 lo = pk2bf(o[nt][0] * inv, o[nt][1] * inv);
      u32 hi = pk2bf(o[nt][2] * inv, o[nt][3] * inv);
      *(uint2*)(ctx + base + nt * 16 + g * 4) = make_uint2(lo, hi);
    }
  };

  for (int r = 0; r < 34; r++) {
    if (r) __syncthreads();  // tile r staged; all waves done with buf r-1

    // prefetch round r+1's K/V tile (overlaps compute; drained at next barrier)
    if (r < 33) {
      const int ktn = (r + 1 < nA) ? (r + 1) : (r + 1 - nA);
      const int nb = (r + 1) & 1;
      int rbase = w * 8;
      gload_lds16(Kg + (size_t)ktn * 4096 + (size_t)(rbase + srow) * 64 + schunk * 8,
                  (char*)(Ks[nb]) + rbase * 128);
      gload_lds16(Vg + (size_t)ktn * 4096 + (size_t)(rbase + srow) * 64 + schunk * 8,
                  (char*)(Vs[nb]) + rbase * 128);
    }

    const bool inA = (r < nA);
    const int kt = inA ? r : (r - nA);
    const int qbase = inA ? qtA * 128 : qtB * 128;
    const int sb0 = qbase + w * 16;  // wave's first q-row
    const int kb = kt * 64;          // round's first key

    if (kb <= sb0 + 15) {  // wave-uniform: wave live this round
      const u16* Kb = Ks[r & 1];
      const u16* Vb = Vs[r & 1];

      // ---- S^T = K . Q^T : 4 key-tiles ----
      f32x4 sa[4];
#pragma unroll
      for (int nt = 0; nt < 4; nt++) {
        bf16x8 k0 = *(const bf16x8*)(Kb + (nt * 16 + c) * 64 + off0);
        bf16x8 k1 = *(const bf16x8*)(Kb + (nt * 16 + c) * 64 + off1);
        f32x4 z = (f32x4){0.f, 0.f, 0.f, 0.f};
        z = MFMA16(k0, aq0, z);  // A=K, B=Q -> S^T[key][q]
        z = MFMA16(k1, aq1, z);
        sa[nt] = z;
      }

      // ---- p = exp2(s), packed P^T write, B-frag read ----
      const bool domask = (kb + 63 > sb0);
      float pe[4][4];
#pragma unroll
      for (int nt = 0; nt < 4; nt++)
#pragma unroll
        for (int rr = 0; rr < 4; rr++) {
          float t = sa[nt][rr];
          if (domask && (kb + nt * 16 + g * 4 + rr) > (sb0 + c)) t = -1e30f;
          pe[nt][rr] = __builtin_amdgcn_exp2f(t);
        }
#pragma unroll
      for (int nt = 0; nt < 4; nt++) {
        u32 lo = pk2bf(pe[nt][0], pe[nt][1]);
        u32 hi = pk2bf(pe[nt][2], pe[nt][3]);
        *(uint2*)(pw + c * 32 + ((nt * 8 + g * 2) ^ sw)) = make_uint2(lo, hi);
      }
      bf16x8 pB0 = *(const bf16x8*)(pw + c * 32 + ((g * 4) ^ sw));
      bf16x8 pB1 = *(const bf16x8*)(pw + c * 32 + ((16 + g * 4) ^ sw));

      // ---- l += P @ 1 on the MFMA pipe ----
      la = MFMA16(onesf, pB0, la);
      la = MFMA16(onesf, pB1, la);

      // ---- O^T += V^T . P^T : 4 d-tiles ----
#pragma unroll
      for (int nt = 0; nt < 4; nt++) {
        bf16x8 v0 = *(const bf16x8*)(Vb + (nt * 16 + c) * 64 + off0);
        bf16x8 v1 = *(const bf16x8*)(Vb + (nt * 16 + c) * 64 + off1);
        o[nt] = MFMA16(v0, pB0, o[nt]);
        o[nt] = MFMA16(v1, pB1, o[nt]);
      }
    }

    // transition: tile A finished -> store, reset, swap to tile B's Q
    if (r == nA - 1) {
      store_tile(qtA * 128);
#pragma unroll
      for (int nt = 0; nt < 4; nt++) o[nt] = (f32x4){0.f, 0.f, 0.f, 0.f};
      la = (f32x4){0.f, 0.f, 0.f, 0.f};
      const u16* QgB = Q + ((size_t)bh * 2048 + qtB * 128) * 64;
      aq0 = *(const bf16x8*)(QgB + (w * 16 + c) * 64 + g * 8);
      aq1 = *(const bf16x8*)(QgB + (w * 16 + c) * 64 + 32 + g * 8);
    }
  }

  store_tile(qtB * 128);
}

// ---------------- out-proj GEMM: out[8192][1024] = ctx @ Woutt^T + bias (fp32 out) ----------------
// BK=64 + chunk-XOR swizzle (R13 form).
__global__ __launch_bounds__(256) void gemm_proj_kernel(const u16* __restrict__ A,
                                                        const u16* __restrict__ Bt,
                                                        const float* __restrict__ bias,
                                                        float* __restrict__ out) {
  __shared__ u16 As[128 * 64];
  __shared__ u16 Bs[128 * 64];
  const int tid = threadIdx.x, w = tid >> 6, lane = tid & 63;
  const int g = lane >> 4, c = lane & 15;
  const int wr = w >> 1, wc = w & 1;
  const int m0 = blockIdx.y * 128, n0 = blockIdx.x * 128;
  const int srow = lane >> 3;
  const int sch = (lane & 7) ^ srow;
  const int cx = c & 7;

  f32x4 acc[4][4];
#pragma unroll
  for (int i = 0; i < 4; i++)
#pragma unroll
    for (int j = 0; j < 4; j++) acc[i][j] = (f32x4){0.f, 0.f, 0.f, 0.f};

  for (int k0 = 0; k0 < 1024; k0 += 64) {
    __syncthreads();
#pragma unroll
    for (int i = 0; i < 4; i++) {
      int row = w * 32 + i * 8;
      gload_lds16(A + (size_t)(m0 + row + srow) * 1024 + k0 + sch * 8,
                  (char*)As + row * 128);
      gload_lds16(Bt + (size_t)(n0 + row + srow) * 1024 + k0 + sch * 8,
                  (char*)Bs + row * 128);
    }
    __syncthreads();

#pragma unroll
    for (int kk = 0; kk < 2; kk++) {
      bf16x8 af[4], bf[4];
#pragma unroll
      for (int mt = 0; mt < 4; mt++)
        af[mt] = *(const bf16x8*)(As + (wr * 64 + mt * 16 + c) * 64 + ((kk * 4 + g) ^ cx) * 8);
#pragma unroll
      for (int nt = 0; nt < 4; nt++)
        bf[nt] = *(const bf16x8*)(Bs + (wc * 64 + nt * 16 + c) * 64 + ((kk * 4 + g) ^ cx) * 8);
#pragma unroll
      for (int mt = 0; mt < 4; mt++)
#pragma unroll
        for (int nt = 0; nt < 4; nt++) acc[mt][nt] = MFMA16(af[mt], bf[nt], acc[mt][nt]);
    }
  }

  float bn[4];
#pragma unroll
  for (int nt = 0; nt < 4; nt++) bn[nt] = bias[n0 + wc * 64 + nt * 16 + c];
#pragma unroll
  for (int mt = 0; mt < 4; mt++)
#pragma unroll
    for (int r = 0; r < 4; r++) {
      int m = m0 + wr * 64 + mt * 16 + g * 4 + r;
#pragma unroll
      for (int nt = 0; nt < 4; nt++) {
        int n = n0 + wc * 64 + nt * 16 + c;
        out[(size_t)m * 1024 + n] = acc[mt][nt][r] + bn[nt];
      }
    }
}

// ---------------- launch ----------------
extern "C" void kernel_launch(void* const* d_in, const int* in_sizes, int n_in,
                              void* d_out, int out_size, void* d_ws, size_t ws_size,
                              hipStream_t stream) {
  const float* x = (const float*)d_in[0];
  const float* Wqkv = (const float*)d_in[1];
  const float* bqkv = (const float*)d_in[2];
  const float* Wout = (const float*)d_in[3];
  const float* bout = (const float*)d_in[4];
  float* out = (float*)d_out;

  char* ws = (char*)d_ws;
  u16* xb  = (u16*)(ws);                    // 16 MB  x bf16 [8192][1024]
  u16* wqt = (u16*)(ws + 16777216);         //  6 MB  Wqkv^T bf16 [3072][1024]
  u16* wot = (u16*)(ws + 23068672);         //  2 MB  Wout^T bf16 [1024][1024]
  u16* Qb  = (u16*)(ws + 25165824);         // 48 MB  QKV bf16 [3][4][16][2048][64]
  u16* Kb  = Qb + 8388608;
  u16* Vb  = Kb + 8388608;
  u16* Vt  = (u16*)(ws + 75497472);         // 16 MB  V^T tiled bf16 [64bh][32kt][64d][64k]
  u16* ctx = (u16*)(ws + 92274688);         // 16 MB  attention out bf16 [8192][1024]

  prep_kernel<<<12288, 256, 0, stream>>>(x, xb, Wqkv, wqt, Wout, wot);
  gemm_qkv_kernel<<<dim3(24, 64), 256, 0, stream>>>(xb, wqt, bqkv, Qb);
  vtrans_kernel<<<dim3(32, 64), 256, 0, stream>>>(Vb, Vt);
  attn_kernel<<<dim3(8, 16, 4), 512, 0, stream>>>(Qb, Kb, Vt, ctx);
  gemm_proj_kernel<<<dim3(8, 64), 256, 0, stream>>>(ctx, wot, bout, out);
}

// Round 13
// 258.230 us; speedup vs baseline: 1.0252x; 1.0075x over previous
//
#include <hip/hip_runtime.h>
#include <hip/hip_bf16.h>
#include <string.h>

// CausalSelfAttention on MI355X (gfx950), bf16 MFMA pipeline.
// R22: R21 (session best, 260.16us) + ONE isolated change: s_setprio(1)
//   around attn's two MFMA clusters (guide m191: +4-7% on attn when resident
//   waves have phase diversity — here 2 independent 8-wave blocks/CU).
//   Pure scheduler hint, zero correctness risk. GEMMs untouched (m190:
//   setprio hurts lockstep GEMM structures).
// Config otherwise == R21/R19: prep fusion; 2-phase BK=64 chunk-XOR GEMMs;
//   vtrans; attn R9 structure (paired 128-row q-tiles, 34 uniform rounds,
//   8 waves x 16 q-rows, K/V dbuf, exp2 softmax, ones-MFMA psum, packed-P
//   LDS round-trip — beats permlane per R20 A/B).
// D=1024, H=16, Hd=64, B=4, T=2048.

typedef unsigned short u16;
typedef unsigned int u32;
typedef __bf16 bf16x8 __attribute__((ext_vector_type(8)));
typedef float f32x4 __attribute__((ext_vector_type(4)));

#define MFMA16(a, b, c) __builtin_amdgcn_mfma_f32_16x16x32_bf16((a), (b), (c), 0, 0, 0)

__device__ __forceinline__ u16 f2bf(float f) {
  unsigned u = __float_as_uint(f);
  u += 0x7fffu + ((u >> 16) & 1u);  // RNE
  return (u16)(u >> 16);
}

__device__ __forceinline__ u32 pk2bf(float a, float b) {
  __hip_bfloat162 h = __float22bfloat162_rn(make_float2(a, b));  // v_cvt_pk_bf16_f32
  u32 r;
  memcpy(&r, &h, 4);  // register-level no-op
  return r;
}

__device__ __forceinline__ void gload_lds16(const void* g, void* l) {
  __builtin_amdgcn_global_load_lds((const __attribute__((address_space(1))) void*)g,
                                   (__attribute__((address_space(3))) void*)l, 16, 0, 0);
}

// ---------------- prep: cast x (fp32->bf16) + transpose-cast both weights ----------------
// blocks [0,8192): cast_x; [8192,11264): tcast Wqkv (96x32); [11264,12288): tcast Wout (32x32)
__global__ __launch_bounds__(256) void prep_kernel(const float* __restrict__ x,
                                                   u16* __restrict__ xb,
                                                   const float* __restrict__ Wqkv,
                                                   u16* __restrict__ wqt,
                                                   const float* __restrict__ Wout,
                                                   u16* __restrict__ wot) {
  const int id = blockIdx.x;
  if (id < 8192) {
    int i = id * 256 + threadIdx.x;
    float4 v = ((const float4*)x)[i];
    ushort4 o;
    o.x = f2bf(v.x); o.y = f2bf(v.y); o.z = f2bf(v.z); o.w = f2bf(v.w);
    ((ushort4*)xb)[i] = o;
    return;
  }
  __shared__ float tile[32][33];
  const float* W; u16* Wt; int N, n0, k0;
  const int K = 1024;
  if (id < 11264) {
    int t = id - 8192;  W = Wqkv; Wt = wqt; N = 3072; n0 = (t % 96) * 32; k0 = (t / 96) * 32;
  } else {
    int t = id - 11264; W = Wout; Wt = wot; N = 1024; n0 = (t % 32) * 32; k0 = (t / 32) * 32;
  }
  int tx = threadIdx.x & 31, ty = threadIdx.x >> 5;  // 32 x 8
#pragma unroll
  for (int i = 0; i < 4; i++) {
    int k = ty + i * 8;
    tile[k][tx] = W[(size_t)(k0 + k) * N + n0 + tx];
  }
  __syncthreads();
#pragma unroll
  for (int i = 0; i < 4; i++) {
    int n = ty + i * 8;
    Wt[(size_t)(n0 + n) * K + k0 + tx] = f2bf(tile[tx][n]);
  }
}

// ---------------- QKV GEMM: C[8192][3072] = xb @ Wqkvt^T + bias, scatter to Q/K/V ----------------
// BK=64, 2-phase, chunk-XOR LDS swizzle. Q cols scaled by log2(e)/8 so
// attention uses raw v_exp_f32 (= 2^x). Coalesced [bh][t][64] scatter.
__global__ __launch_bounds__(256) void gemm_qkv_kernel(const u16* __restrict__ A,
                                                       const u16* __restrict__ Bt,
                                                       const float* __restrict__ bias,
                                                       u16* __restrict__ QKV) {
  __shared__ u16 As[128 * 64];  // 16 KB
  __shared__ u16 Bs[128 * 64];  // 16 KB
  const int tid = threadIdx.x, w = tid >> 6, lane = tid & 63;
  const int g = lane >> 4, c = lane & 15;
  const int wr = w >> 1, wc = w & 1;
  const int m0 = blockIdx.y * 128, n0 = blockIdx.x * 128;
  const int srow = lane >> 3;                 // 0..7 within 8-row group
  const int sch = (lane & 7) ^ srow;          // inverse-swizzled source chunk
  const int cx = c & 7;                       // read-side row&7

  f32x4 acc[4][4];
#pragma unroll
  for (int i = 0; i < 4; i++)
#pragma unroll
    for (int j = 0; j < 4; j++) acc[i][j] = (f32x4){0.f, 0.f, 0.f, 0.f};

  for (int k0 = 0; k0 < 1024; k0 += 64) {
    __syncthreads();
#pragma unroll
    for (int i = 0; i < 4; i++) {
      int row = w * 32 + i * 8;  // wave stages rows w*32..w*32+31 (8/instr)
      gload_lds16(A + (size_t)(m0 + row + srow) * 1024 + k0 + sch * 8,
                  (char*)As + row * 128);
      gload_lds16(Bt + (size_t)(n0 + row + srow) * 1024 + k0 + sch * 8,
                  (char*)Bs + row * 128);
    }
    __syncthreads();

#pragma unroll
    for (int kk = 0; kk < 2; kk++) {
      bf16x8 af[4], bf[4];
#pragma unroll
      for (int mt = 0; mt < 4; mt++)
        af[mt] = *(const bf16x8*)(As + (wr * 64 + mt * 16 + c) * 64 + ((kk * 4 + g) ^ cx) * 8);
#pragma unroll
      for (int nt = 0; nt < 4; nt++)
        bf[nt] = *(const bf16x8*)(Bs + (wc * 64 + nt * 16 + c) * 64 + ((kk * 4 + g) ^ cx) * 8);
#pragma unroll
      for (int mt = 0; mt < 4; mt++)
#pragma unroll
        for (int nt = 0; nt < 4; nt++) acc[mt][nt] = MFMA16(af[mt], bf[nt], acc[mt][nt]);
    }
  }

  const float qscale = (n0 < 1024) ? 0.18033688011112042f : 1.0f;  // log2(e)/8
  float bn[4];
#pragma unroll
  for (int nt = 0; nt < 4; nt++) bn[nt] = bias[n0 + wc * 64 + nt * 16 + c];
#pragma unroll
  for (int mt = 0; mt < 4; mt++) {
#pragma unroll
    for (int r = 0; r < 4; r++) {
      int m = m0 + wr * 64 + mt * 16 + g * 4 + r;  // token index
      int bb = m >> 11, t = m & 2047;
#pragma unroll
      for (int nt = 0; nt < 4; nt++) {
        int n = n0 + wc * 64 + nt * 16 + c;
        int which = n >> 10, rem = n & 1023, h = rem >> 6, d = rem & 63;
        float v = (acc[mt][nt][r] + bn[nt]) * qscale;
        QKV[(size_t)which * 8388608 + (((size_t)(bb * 16 + h) * 2048 + t) * 64 + d)] = f2bf(v);
      }
    }
  }
}

// ---------------- V transpose: V[bh][2048][64] -> Vt tiled [bh][kt][64d][64k] ----------------
__global__ __launch_bounds__(256) void vtrans_kernel(const u16* __restrict__ V,
                                                     u16* __restrict__ Vt) {
  __shared__ u16 tile[64][65];
  int bh = blockIdx.y;
  int kt = blockIdx.x;
  int t0 = kt * 64;
  int tx = threadIdx.x & 63, ty = threadIdx.x >> 6;  // 64 x 4
  const u16* src = V + ((size_t)bh * 2048 + t0) * 64;
#pragma unroll
  for (int i = 0; i < 16; i++) {
    int tr = i * 4 + ty;
    tile[tr][tx] = src[tr * 64 + tx];
  }
  __syncthreads();
  u16* dst = Vt + ((size_t)(bh * 32 + kt)) * 4096;  // [64d][64k] tile
#pragma unroll
  for (int i = 0; i < 16; i++) {
    int d = i * 4 + ty;
    dst[d * 64 + tx] = tile[tx][d];
  }
}

// ---------------- flash attention: paired 128-row q-tiles, 8 waves x 16 q-rows ----------------
// grid (8 pairs, 16 heads, 4 batch), 512 threads (8 waves). Block handles
// q-tiles p and 15-p (128 rows each) sequentially: 34 uniform rounds.
// Wave w owns q-rows tile_base + w*16 .. +16. K/V staged in LDS dbuf (one
// gload each per wave per round), one barrier per round. S^T = mfma(K, Q);
// p = exp2(s) (Q pre-scaled by log2e/8); l via ones-MFMA psum; packed P/ctx.
// setprio(1) around MFMA clusters (cross-block wave arbitration, m191).
__global__ __launch_bounds__(512, 4) void attn_kernel(const u16* __restrict__ Q,
                                                      const u16* __restrict__ K,
                                                      const u16* __restrict__ Vt,
                                                      u16* __restrict__ ctx) {
  const int pr = blockIdx.x;          // 0..7
  const int qtA = pr, qtB = 15 - pr;  // paired 128-row q-tiles
  const int h = blockIdx.y, b = blockIdx.z;
  const int bh = b * 16 + h;
  const int tid = threadIdx.x, w = tid >> 6, lane = tid & 63;
  const int g = lane >> 4, c = lane & 15;

  const u16* Kg = K + (size_t)bh * 2048 * 64;   // [T][64]
  const u16* Vg = Vt + (size_t)bh * 32 * 4096;  // tiled [kt][64d][64k]

  __shared__ u16 Ks[2][64 * 64];   // K dbuf, XOR-swizzled chunks (16 KB)
  __shared__ u16 Vs[2][64 * 64];   // V dbuf (16 KB)
  __shared__ u32 Pw[8][16 * 32];   // wave-private packed P^T (16 KB)
  u32* pw = Pw[w];

  // staging lane map (verified swizzle); wave w stages rows w*8..w*8+8
  const int srow = lane >> 3;
  const int schunk = (lane & 7) ^ (srow & 7);
  const int cx = c & 7;
  const int off0 = ((g ^ cx) * 8);        // chunk g   (u16 offset)
  const int off1 = (((g ^ cx) ^ 4) * 8);  // chunk g^4
  const int sw = cx << 2;                 // P-buffer 4-dword-block swizzle

  // constant all-ones A-fragment for the psum MFMA
  bf16x8 onesf;
#pragma unroll
  for (int i = 0; i < 8; i++) onesf[i] = (__bf16)1.0f;

  // Q B-fragments for tile A (wave's 16 q-rows; dims 0-31 / 32-63)
  const u16* QgA = Q + ((size_t)bh * 2048 + qtA * 128) * 64;
  bf16x8 aq0 = *(const bf16x8*)(QgA + (w * 16 + c) * 64 + g * 8);
  bf16x8 aq1 = *(const bf16x8*)(QgA + (w * 16 + c) * 64 + 32 + g * 8);

  // prologue: stage K/V tile 0 (1 gload each per wave)
  {
    int rbase = w * 8;
    gload_lds16(Kg + (size_t)(rbase + srow) * 64 + schunk * 8, (char*)(Ks[0]) + rbase * 128);
    gload_lds16(Vg + (size_t)(rbase + srow) * 64 + schunk * 8, (char*)(Vs[0]) + rbase * 128);
  }
  __syncthreads();

  f32x4 o[4], la;
#pragma unroll
  for (int nt = 0; nt < 4; nt++) o[nt] = (f32x4){0.f, 0.f, 0.f, 0.f};
  la = (f32x4){0.f, 0.f, 0.f, 0.f};

  const int nA = 2 * qtA + 2;  // rounds in tile A

  // normalize + packed 8B stores for one finished q-tile (wave's 16 rows)
  auto store_tile = [&](int qbase) {
    float inv = 1.f / la[0];
    int q = qbase + w * 16 + c;
    size_t base = ((size_t)(b * 2048 + q)) * 1024 + h * 64;
#pragma unroll
    for (int nt = 0; nt < 4; nt++) {
      u32 lo = pk2bf(o[nt][0] * inv, o[nt][1] * inv);
      u32 hi = pk2bf(o[nt][2] * inv, o[nt][3] * inv);
      *(uint2*)(ctx + base + nt * 16 + g * 4) = make_uint2(lo, hi);
    }
  };

  for (int r = 0; r < 34; r++) {
    if (r) __syncthreads();  // tile r staged; all waves done with buf r-1

    // prefetch round r+1's K/V tile (overlaps compute; drained at next barrier)
    if (r < 33) {
      const int ktn = (r + 1 < nA) ? (r + 1) : (r + 1 - nA);
      const int nb = (r + 1) & 1;
      int rbase = w * 8;
      gload_lds16(Kg + (size_t)ktn * 4096 + (size_t)(rbase + srow) * 64 + schunk * 8,
                  (char*)(Ks[nb]) + rbase * 128);
      gload_lds16(Vg + (size_t)ktn * 4096 + (size_t)(rbase + srow) * 64 + schunk * 8,
                  (char*)(Vs[nb]) + rbase * 128);
    }

    const bool inA = (r < nA);
    const int kt = inA ? r : (r - nA);
    const int qbase = inA ? qtA * 128 : qtB * 128;
    const int sb0 = qbase + w * 16;  // wave's first q-row
    const int kb = kt * 64;          // round's first key

    if (kb <= sb0 + 15) {  // wave-uniform: wave live this round
      const u16* Kb = Ks[r & 1];
      const u16* Vb = Vs[r & 1];

      // ---- S^T = K . Q^T : 4 key-tiles ----
      __builtin_amdgcn_s_setprio(1);
      f32x4 sa[4];
#pragma unroll
      for (int nt = 0; nt < 4; nt++) {
        bf16x8 k0 = *(const bf16x8*)(Kb + (nt * 16 + c) * 64 + off0);
        bf16x8 k1 = *(const bf16x8*)(Kb + (nt * 16 + c) * 64 + off1);
        f32x4 z = (f32x4){0.f, 0.f, 0.f, 0.f};
        z = MFMA16(k0, aq0, z);  // A=K, B=Q -> S^T[key][q]
        z = MFMA16(k1, aq1, z);
        sa[nt] = z;
      }
      __builtin_amdgcn_s_setprio(0);

      // ---- p = exp2(s), packed P^T write, B-frag read ----
      const bool domask = (kb + 63 > sb0);
      float pe[4][4];
#pragma unroll
      for (int nt = 0; nt < 4; nt++)
#pragma unroll
        for (int rr = 0; rr < 4; rr++) {
          float t = sa[nt][rr];
          if (domask && (kb + nt * 16 + g * 4 + rr) > (sb0 + c)) t = -1e30f;
          pe[nt][rr] = __builtin_amdgcn_exp2f(t);
        }
#pragma unroll
      for (int nt = 0; nt < 4; nt++) {
        u32 lo = pk2bf(pe[nt][0], pe[nt][1]);
        u32 hi = pk2bf(pe[nt][2], pe[nt][3]);
        *(uint2*)(pw + c * 32 + ((nt * 8 + g * 2) ^ sw)) = make_uint2(lo, hi);
      }
      bf16x8 pB0 = *(const bf16x8*)(pw + c * 32 + ((g * 4) ^ sw));
      bf16x8 pB1 = *(const bf16x8*)(pw + c * 32 + ((16 + g * 4) ^ sw));

      // ---- l += P @ 1 ; O^T += V^T . P^T : 4 d-tiles ----
      __builtin_amdgcn_s_setprio(1);
      la = MFMA16(onesf, pB0, la);
      la = MFMA16(onesf, pB1, la);
#pragma unroll
      for (int nt = 0; nt < 4; nt++) {
        bf16x8 v0 = *(const bf16x8*)(Vb + (nt * 16 + c) * 64 + off0);
        bf16x8 v1 = *(const bf16x8*)(Vb + (nt * 16 + c) * 64 + off1);
        o[nt] = MFMA16(v0, pB0, o[nt]);
        o[nt] = MFMA16(v1, pB1, o[nt]);
      }
      __builtin_amdgcn_s_setprio(0);
    }

    // transition: tile A finished -> store, reset, swap to tile B's Q
    if (r == nA - 1) {
      store_tile(qtA * 128);
#pragma unroll
      for (int nt = 0; nt < 4; nt++) o[nt] = (f32x4){0.f, 0.f, 0.f, 0.f};
      la = (f32x4){0.f, 0.f, 0.f, 0.f};
      const u16* QgB = Q + ((size_t)bh * 2048 + qtB * 128) * 64;
      aq0 = *(const bf16x8*)(QgB + (w * 16 + c) * 64 + g * 8);
      aq1 = *(const bf16x8*)(QgB + (w * 16 + c) * 64 + 32 + g * 8);
    }
  }

  store_tile(qtB * 128);
}

// ---------------- out-proj GEMM: out[8192][1024] = ctx @ Woutt^T + bias (fp32 out) ----------------
// BK=64 + chunk-XOR swizzle (R13 form).
__global__ __launch_bounds__(256) void gemm_proj_kernel(const u16* __restrict__ A,
                                                        const u16* __restrict__ Bt,
                                                        const float* __restrict__ bias,
                                                        float* __restrict__ out) {
  __shared__ u16 As[128 * 64];
  __shared__ u16 Bs[128 * 64];
  const int tid = threadIdx.x, w = tid >> 6, lane = tid & 63;
  const int g = lane >> 4, c = lane & 15;
  const int wr = w >> 1, wc = w & 1;
  const int m0 = blockIdx.y * 128, n0 = blockIdx.x * 128;
  const int srow = lane >> 3;
  const int sch = (lane & 7) ^ srow;
  const int cx = c & 7;

  f32x4 acc[4][4];
#pragma unroll
  for (int i = 0; i < 4; i++)
#pragma unroll
    for (int j = 0; j < 4; j++) acc[i][j] = (f32x4){0.f, 0.f, 0.f, 0.f};

  for (int k0 = 0; k0 < 1024; k0 += 64) {
    __syncthreads();
#pragma unroll
    for (int i = 0; i < 4; i++) {
      int row = w * 32 + i * 8;
      gload_lds16(A + (size_t)(m0 + row + srow) * 1024 + k0 + sch * 8,
                  (char*)As + row * 128);
      gload_lds16(Bt + (size_t)(n0 + row + srow) * 1024 + k0 + sch * 8,
                  (char*)Bs + row * 128);
    }
    __syncthreads();

#pragma unroll
    for (int kk = 0; kk < 2; kk++) {
      bf16x8 af[4], bf[4];
#pragma unroll
      for (int mt = 0; mt < 4; mt++)
        af[mt] = *(const bf16x8*)(As + (wr * 64 + mt * 16 + c) * 64 + ((kk * 4 + g) ^ cx) * 8);
#pragma unroll
      for (int nt = 0; nt < 4; nt++)
        bf[nt] = *(const bf16x8*)(Bs + (wc * 64 + nt * 16 + c) * 64 + ((kk * 4 + g) ^ cx) * 8);
#pragma unroll
      for (int mt = 0; mt < 4; mt++)
#pragma unroll
        for (int nt = 0; nt < 4; nt++) acc[mt][nt] = MFMA16(af[mt], bf[nt], acc[mt][nt]);
    }
  }

  float bn[4];
#pragma unroll
  for (int nt = 0; nt < 4; nt++) bn[nt] = bias[n0 + wc * 64 + nt * 16 + c];
#pragma unroll
  for (int mt = 0; mt < 4; mt++)
#pragma unroll
    for (int r = 0; r < 4; r++) {
      int m = m0 + wr * 64 + mt * 16 + g * 4 + r;
#pragma unroll
      for (int nt = 0; nt < 4; nt++) {
        int n = n0 + wc * 64 + nt * 16 + c;
        out[(size_t)m * 1024 + n] = acc[mt][nt][r] + bn[nt];
      }
    }
}

// ---------------- launch ----------------
extern "C" void kernel_launch(void* const* d_in, const int* in_sizes, int n_in,
                              void* d_out, int out_size, void* d_ws, size_t ws_size,
                              hipStream_t stream) {
  const float* x = (const float*)d_in[0];
  const float* Wqkv = (const float*)d_in[1];
  const float* bqkv = (const float*)d_in[2];
  const float* Wout = (const float*)d_in[3];
  const float* bout = (const float*)d_in[4];
  float* out = (float*)d_out;

  char* ws = (char*)d_ws;
  u16* xb  = (u16*)(ws);                    // 16 MB  x bf16 [8192][1024]
  u16* wqt = (u16*)(ws + 16777216);         //  6 MB  Wqkv^T bf16 [3072][1024]
  u16* wot = (u16*)(ws + 23068672);         //  2 MB  Wout^T bf16 [1024][1024]
  u16* Qb  = (u16*)(ws + 25165824);         // 48 MB  QKV bf16 [3][4][16][2048][64]
  u16* Kb  = Qb + 8388608;
  u16* Vb  = Kb + 8388608;
  u16* Vt  = (u16*)(ws + 75497472);         // 16 MB  V^T tiled bf16 [64bh][32kt][64d][64k]
  u16* ctx = (u16*)(ws + 92274688);         // 16 MB  attention out bf16 [8192][1024]

  prep_kernel<<<12288, 256, 0, stream>>>(x, xb, Wqkv, wqt, Wout, wot);
  gemm_qkv_kernel<<<dim3(24, 64), 256, 0, stream>>>(xb, wqt, bqkv, Qb);
  vtrans_kernel<<<dim3(32, 64), 256, 0, stream>>>(Vb, Vt);
  attn_kernel<<<dim3(8, 16, 4), 512, 0, stream>>>(Qb, Kb, Vt, ctx);
  gemm_proj_kernel<<<dim3(8, 64), 256, 0, stream>>>(ctx, wot, bout, out);
}